// Round 6
// baseline (948.199 us; speedup 1.0000x reference)
//
#include <hip/hip_runtime.h>
#include <stdint.h>

// MGMCGCN — 3x (binary-GCN + 5-step LSTM + fc/tanh).
// Dtypes: float inputs f32, adj int32, ALL OUTPUTS f32. Internal bf16 MFMA.
// N=4096, F=H=256, K=3, T=5, G=4H=1024.
#define NN_ 4096
#define FD 256
#define HD 256
#define KC 3
#define GD 1024
#define SA 40    // padded LDS pitch (shorts): 80 B row stride, 16B-aligned, 2-way-free
#define PAG 40
#define HP 264   // lstm h pitch (528 B, 16B-aligned, 2-way-free)
#define BP 40    // lstm W pitch

typedef __attribute__((ext_vector_type(4))) unsigned int vu4;     // 16 B
typedef __attribute__((ext_vector_type(4))) int vi4;              // 16 B
typedef __attribute__((ext_vector_type(4))) float vf4;            // 16 B
typedef __attribute__((ext_vector_type(4))) unsigned short vus4;  // 8 B
typedef __attribute__((ext_vector_type(8))) short short8;         // bf16x8 MFMA frag
typedef __attribute__((ext_vector_type(4))) float f32x4;          // MFMA acc

__device__ __forceinline__ float b2f(unsigned short u) {
    unsigned int v = ((unsigned int)u) << 16; float f; __builtin_memcpy(&f, &v, 4); return f;
}
__device__ __forceinline__ unsigned short f2b(float x) {
    unsigned int u; __builtin_memcpy(&u, &x, 4);
    u = (u + 0x7FFFu + ((u >> 16) & 1u)) >> 16;   // RNE
    return (unsigned short)u;
}
__device__ __forceinline__ void cvt8(const float* __restrict__ g, unsigned short* o) {
    vf4 a = *(const vf4*)g, b = *(const vf4*)(g + 4);
    o[0] = f2b(a[0]); o[1] = f2b(a[1]); o[2] = f2b(a[2]); o[3] = f2b(a[3]);
    o[4] = f2b(b[0]); o[5] = f2b(b[1]); o[6] = f2b(b[2]); o[7] = f2b(b[3]);
}
__device__ __forceinline__ float sigm(float v) { return 1.f / (1.f + __expf(-v)); }

// ---------------------------------------------------------------------------
// adj_pass v2: read adj int32 [N][N][K]; write (a) f32 0/1 interleaved copy to
// d_out adj region, (b) bf16 deinterleaved planes abk[k][i][j] for gemm_agg;
// compute dinv[k][i]. Thread handles 4 j x 3 k = 12 ints -> direct k-sums.
// ---------------------------------------------------------------------------
__global__ __launch_bounds__(256) void adj_pass(const int* __restrict__ adj,
        float* __restrict__ adj_out, unsigned short* __restrict__ abk,
        float* __restrict__ dinv) {
    const int i = blockIdx.x, t = threadIdx.x;
    const int* src = adj + (size_t)i * 12288;
    float* dstf = adj_out + (size_t)i * 12288;
    float s0 = 0.f, s1 = 0.f, s2 = 0.f;
#pragma unroll
    for (int it = 0; it < 4; ++it) {
        int jq = (it * 256 + t) * 4;
        vi4 a = *(const vi4*)(src + jq * 3);
        vi4 b = *(const vi4*)(src + jq * 3 + 4);
        vi4 c = *(const vi4*)(src + jq * 3 + 8);
        int vv[12] = {a[0],a[1],a[2],a[3],b[0],b[1],b[2],b[3],c[0],c[1],c[2],c[3]};
        float ff[12];
#pragma unroll
        for (int e = 0; e < 12; ++e) ff[e] = vv[e] ? 1.f : 0.f;
        vf4 w0 = {ff[0],ff[1],ff[2],ff[3]}, w1 = {ff[4],ff[5],ff[6],ff[7]}, w2 = {ff[8],ff[9],ff[10],ff[11]};
        *(vf4*)(dstf + jq * 3) = w0; *(vf4*)(dstf + jq * 3 + 4) = w1; *(vf4*)(dstf + jq * 3 + 8) = w2;
#pragma unroll
        for (int k = 0; k < 3; ++k) {
            vus4 w;
            w[0] = vv[k]     ? (unsigned short)0x3F80 : (unsigned short)0;
            w[1] = vv[3 + k] ? (unsigned short)0x3F80 : (unsigned short)0;
            w[2] = vv[6 + k] ? (unsigned short)0x3F80 : (unsigned short)0;
            w[3] = vv[9 + k] ? (unsigned short)0x3F80 : (unsigned short)0;
            *(vus4*)(abk + ((size_t)(k * NN_ + i)) * NN_ + jq) = w;
        }
        s0 += ff[0] + ff[3] + ff[6] + ff[9];
        s1 += ff[1] + ff[4] + ff[7] + ff[10];
        s2 += ff[2] + ff[5] + ff[8] + ff[11];
    }
    __shared__ float r0[256], r1[256], r2[256];
    r0[t] = s0; r1[t] = s1; r2[t] = s2;
    __syncthreads();
    for (int off = 128; off > 0; off >>= 1) {
        if (t < off) { r0[t] += r0[t + off]; r1[t] += r1[t + off]; r2[t] += r2[t + off]; }
        __syncthreads();
    }
    if (t == 0) {
        dinv[i]            = 1.f / sqrtf(1.f + r0[0]);
        dinv[NN_ + i]      = 1.f / sqrtf(1.f + r1[0]);
        dinv[2 * NN_ + i]  = 1.f / sqrtf(1.f + r2[0]);
    }
}

// ---------------------------------------------------------------------------
// wcvt: one-time f32->bf16 of [wih | whh | fcw] into contiguous wb.
// ---------------------------------------------------------------------------
__global__ __launch_bounds__(256) void wcvt(const float* __restrict__ wih,
        const float* __restrict__ whh, const float* __restrict__ fcw,
        unsigned short* __restrict__ wb) {
    size_t e = ((size_t)blockIdx.x * 256 + threadIdx.x) * 8;
    const float* src; size_t off;
    if (e < 786432)       { src = wih; off = e; }
    else if (e < 1572864) { src = whh; off = e - 786432; }
    else                  { src = fcw; off = e - 1572864; }
    alignas(16) unsigned short o[8];
    cvt8(src + off, o);
    *(vu4*)(wb + e) = *(vu4*)o;
}

// ---------------------------------------------------------------------------
// GEMM1: yT[k][h][j] = dinv[k][j] * (x @ gnn_w[k])[j][h] (transposed store).
// ---------------------------------------------------------------------------
__global__ __launch_bounds__(256) void gemm_xw(const float* __restrict__ x,
        const float* __restrict__ gw, const float* __restrict__ dinv,
        unsigned short* __restrict__ yT) {
    __shared__ __align__(16) unsigned short sA[64 * SA], sB[64 * SA];
    const int bi = blockIdx.x, bj = blockIdx.y, k = blockIdx.z;
    const int t = threadIdx.x, lane = t & 63, wave = t >> 6;
    const int m = lane & 15, q = lane >> 4, ko = q * 8;
    const int h0 = bj * 64;
    f32x4 acc[4] = {};
    const float* A0 = x + (size_t)(bi * 64) * FD;
    const float* B0 = gw + (size_t)k * FD * HD;
    const int r = t >> 2, c8 = (t & 3) << 3;
    const int fB = t >> 3, c8B = (t & 7) << 3;
    for (int k0 = 0; k0 < FD; k0 += 32) {
        alignas(16) unsigned short tA[8], tB[8];
        cvt8(A0 + (size_t)r * FD + k0 + c8, tA);
        *(vu4*)(sA + r * SA + c8) = *(vu4*)tA;
        cvt8(B0 + (size_t)(k0 + fB) * HD + h0 + c8B, tB);
#pragma unroll
        for (int e = 0; e < 8; ++e) sB[(c8B + e) * SA + fB] = tB[e];
        __syncthreads();
        short8 af = *(const short8*)(sA + (wave * 16 + m) * SA + ko);
#pragma unroll
        for (int ct = 0; ct < 4; ++ct) {
            short8 bf = *(const short8*)(sB + (ct * 16 + m) * SA + ko);
            acc[ct] = __builtin_amdgcn_mfma_f32_16x16x32_bf16(af, bf, acc[ct], 0, 0, 0);
        }
        __syncthreads();
    }
    unsigned short* yTk = yT + (size_t)k * HD * NN_;
#pragma unroll
    for (int ct = 0; ct < 4; ++ct)
#pragma unroll
        for (int r2 = 0; r2 < 4; ++r2) {
            int col = h0 + ct * 16 + m;
            int row = bi * 64 + wave * 16 + q * 4 + r2;
            yTk[(size_t)col * NN_ + row] = f2b(acc[ct][r2] * dinv[(size_t)k * NN_ + row]);
        }
}

// ---------------------------------------------------------------------------
// GEMM2 (j-split): pbuf[s][k][i][h] = sum_{j in chunk s} A_k[i][j]*y_k[j][h]
//   (+ self y_k[i][h] in the chunk containing j==i). A = bf16 planes abk.
// Block 64i x 128h x 1024j, waves 2x2, grid (2,64,4)=512.
// ---------------------------------------------------------------------------
__global__ __launch_bounds__(256) void gemm_agg(const unsigned short* __restrict__ abk,
        const unsigned short* __restrict__ yT, unsigned short* __restrict__ pbuf) {
    __shared__ __align__(16) unsigned short sA[3][64 * PAG];
    __shared__ __align__(16) unsigned short sB[3][128 * PAG];
    const int bh = blockIdx.x, bi = blockIdx.y, s = blockIdx.z;
    const int t = threadIdx.x, lane = t & 63, wave = t >> 6;
    const int wi = wave & 1, wh = wave >> 1;
    const int m = lane & 15, q = lane >> 4, ko = q * 8;
    const int i0 = bi * 64, h0 = bh * 128, jbase = s * 1024;
    f32x4 acc[3][2][4] = {};
    const int rA = t >> 2, jg = (t & 3) << 3;       // A: 64 rows x 32 j per plane
    const int rB = (t & 511) >> 2;                   // reuse pattern for B below
    for (int j0 = 0; j0 < 1024; j0 += 32) {
#pragma unroll
        for (int p = 0; p < 3; ++p)
            *(vu4*)(&sA[p][rA * PAG + jg]) =
                *(const vu4*)(abk + ((size_t)(p * NN_ + i0 + rA)) * NN_ + jbase + j0 + jg);
#pragma unroll
        for (int it = 0; it < 6; ++it) {
            int e = it * 256 + t, k = e >> 9, r = (e & 511) >> 2, c = (e & 3) << 3;
            *(vu4*)(&sB[k][r * PAG + c]) =
                *(const vu4*)(yT + (size_t)(k * 256 + h0 + r) * 4096 + jbase + j0 + c);
        }
        __syncthreads();
        short8 aF[3][2];
#pragma unroll
        for (int k = 0; k < 3; ++k)
#pragma unroll
            for (int rt = 0; rt < 2; ++rt)
                aF[k][rt] = *(const short8*)(&sA[k][(wi * 32 + rt * 16 + m) * PAG + ko]);
#pragma unroll
        for (int k = 0; k < 3; ++k)
#pragma unroll
            for (int ct = 0; ct < 4; ++ct) {
                short8 bF = *(const short8*)(&sB[k][(wh * 64 + ct * 16 + m) * PAG + ko]);
#pragma unroll
                for (int rt = 0; rt < 2; ++rt)
                    acc[k][rt][ct] = __builtin_amdgcn_mfma_f32_16x16x32_bf16(aF[k][rt], bF, acc[k][rt][ct], 0, 0, 0);
            }
        __syncthreads();
    }
    (void)rB;
    const int addself = (s == (i0 >> 10));
#pragma unroll
    for (int k = 0; k < 3; ++k)
#pragma unroll
        for (int rt = 0; rt < 2; ++rt)
#pragma unroll
            for (int ct = 0; ct < 4; ++ct)
#pragma unroll
                for (int r2 = 0; r2 < 4; ++r2) {
                    int row = i0 + wi * 32 + rt * 16 + q * 4 + r2;
                    int col = h0 + wh * 64 + ct * 16 + m;
                    float v = acc[k][rt][ct][r2];
                    if (addself) v += b2f(yT[((size_t)k * 256 + col) * 4096 + row]);
                    pbuf[(((size_t)s * 3 + k) * 4096 + row) * 256 + col] = f2b(v);
                }
}

// ---------------------------------------------------------------------------
// agg_reduce: xt[k][i][h] = f2b(dinv[k][i] * (sum_s pbuf[s]) + gnnb[k][h])
// ---------------------------------------------------------------------------
__global__ __launch_bounds__(256) void agg_reduce(const unsigned short* __restrict__ pbuf,
        const float* __restrict__ dinv, const float* __restrict__ gnnb,
        unsigned short* __restrict__ xt) {
    size_t e8 = ((size_t)blockIdx.x * 256 + threadIdx.x) * 8;
    int k = (int)(e8 >> 20);
    int i = (int)((e8 >> 8) & 4095);
    int h = (int)(e8 & 255);
    float di = dinv[k * NN_ + i];
    const size_t KIH = (size_t)KC * NN_ * HD;
    alignas(16) unsigned short p0[8], p1[8], p2[8], p3[8], o[8];
    *(vu4*)p0 = *(const vu4*)(pbuf + 0 * KIH + e8);
    *(vu4*)p1 = *(const vu4*)(pbuf + 1 * KIH + e8);
    *(vu4*)p2 = *(const vu4*)(pbuf + 2 * KIH + e8);
    *(vu4*)p3 = *(const vu4*)(pbuf + 3 * KIH + e8);
#pragma unroll
    for (int e = 0; e < 8; ++e) {
        float v = b2f(p0[e]) + b2f(p1[e]) + b2f(p2[e]) + b2f(p3[e]);
        o[e] = f2b(di * v + gnnb[k * HD + h + e]);
    }
    *(vu4*)(xt + e8) = *(vu4*)o;
}

// ---------------------------------------------------------------------------
// NT GEMM: out = ep(A . W^T + b1 + b2). gate_ilv=1 -> gateX layout
// [k][n][ch][4 gates] (col = gate*256+ch); else plain [k][n][COLS].
// ---------------------------------------------------------------------------
__global__ __launch_bounds__(256) void gemm_nt_ep(const unsigned short* __restrict__ A,
        const unsigned short* __restrict__ W, const float* __restrict__ b1,
        const float* __restrict__ b2, unsigned short* __restrict__ outp,
        int COLS, int do_tanh, int gate_ilv) {
    __shared__ __align__(16) unsigned short sA[64 * SA], sB[64 * SA];
    const int bg = blockIdx.x, bn = blockIdx.y, k = blockIdx.z;
    const int t = threadIdx.x, lane = t & 63, wave = t >> 6;
    const int m = lane & 15, q = lane >> 4, ko = q * 8;
    f32x4 acc[4] = {};
    const unsigned short* A0 = A + ((size_t)k * NN_ + bn * 64) * HD;
    const unsigned short* W0 = W + ((size_t)k * COLS + bg * 64) * HD;
    const int r = t >> 2, c8 = (t & 3) << 3;
    for (int k0 = 0; k0 < HD; k0 += 32) {
        *(vu4*)(sA + r * SA + c8) = *(const vu4*)(A0 + (size_t)r * HD + k0 + c8);
        *(vu4*)(sB + r * SA + c8) = *(const vu4*)(W0 + (size_t)r * HD + k0 + c8);
        __syncthreads();
        short8 af = *(const short8*)(sA + (wave * 16 + m) * SA + ko);
#pragma unroll
        for (int ct = 0; ct < 4; ++ct) {
            short8 bf = *(const short8*)(sB + (ct * 16 + m) * SA + ko);
            acc[ct] = __builtin_amdgcn_mfma_f32_16x16x32_bf16(af, bf, acc[ct], 0, 0, 0);
        }
        __syncthreads();
    }
#pragma unroll
    for (int ct = 0; ct < 4; ++ct)
#pragma unroll
        for (int r2 = 0; r2 < 4; ++r2) {
            int col = bg * 64 + ct * 16 + m;
            int row = bn * 64 + wave * 16 + q * 4 + r2;
            float v = acc[ct][r2];
            if (b1) v += b1[(size_t)k * COLS + col];
            if (b2) v += b2[(size_t)k * COLS + col];
            if (do_tanh) v = tanhf(v);
            if (gate_ilv) {
                int gate = col >> 8, ch = col & 255;
                outp[(((size_t)k * NN_ + row) * 256 + ch) * 4 + gate] = f2b(v);
            } else {
                outp[((size_t)k * NN_ + row) * COLS + col] = f2b(v);
            }
        }
}

// ---------------------------------------------------------------------------
// lstm_fused: ALL 5 timesteps in one kernel. Block = 32 rows x all 1024 gate
// cols, k fixed; grid (128,3)=384. h persists in LDS (A-operand layout), c in
// f32 registers (each wave covers a 32-ch strip across ALL 4 gates -> lane
// holds i,f,g,o for its own (row,col) elems). W_hh restaged from L2 per step
// in two 512-row halves (LDS 57 KB total < 64 KB).
// ---------------------------------------------------------------------------
__global__ __launch_bounds__(256) void lstm_fused(const unsigned short* __restrict__ gX2,
        const unsigned short* __restrict__ whhb, unsigned short* __restrict__ hout) {
    __shared__ __align__(16) unsigned short sH[32 * HP];    // 16.9 KB
    __shared__ __align__(16) unsigned short sB[512 * BP];   // 40.0 KB
    const int t = threadIdx.x, lane = t & 63, wh = t >> 6;  // wh = col strip 0..3
    const int m = lane & 15, q = lane >> 4, ko = q * 8;
    const int bi = blockIdx.x, k = blockIdx.y;
    const int n0 = bi * 32;
    const unsigned short* W0 = whhb + (size_t)k * GD * HD;
    const unsigned short* gX = gX2 + ((size_t)(k * NN_ + n0)) * 1024;  // [row][ch][4]
    float c[2][4][4] = {};   // [rt][cc][r2]
    for (int step = 0; step < 5; ++step) {
        f32x4 acc[2][4][4] = {};   // [rt][gate][cc]
        if (step > 0) {
            for (int k0 = 0; k0 < 256; k0 += 32) {
#pragma unroll
                for (int hf = 0; hf < 2; ++hf) {
                    // stage 512 W rows (gates x 128-ch half) x 32 K
#pragma unroll
                    for (int it = 0; it < 8; ++it) {
                        int e = it * 256 + t, r = e >> 2, c8 = (e & 3) << 3;
                        int g = r >> 7, ch = hf * 128 + (r & 127);
                        *(vu4*)(&sB[r * BP + c8]) =
                            *(const vu4*)(W0 + (size_t)(g * 256 + ch) * 256 + k0 + c8);
                    }
                    __syncthreads();
                    short8 af[2];
#pragma unroll
                    for (int rt = 0; rt < 2; ++rt)
                        af[rt] = *(const short8*)(&sH[(rt * 16 + m) * HP + k0 + ko]);
#pragma unroll
                    for (int g = 0; g < 4; ++g)
#pragma unroll
                        for (int c2 = 0; c2 < 2; ++c2) {
                            short8 bf = *(const short8*)(&sB[(g * 128 + wh * 32 + c2 * 16 + m) * BP + ko]);
                            int cc = hf * 2 + c2;
#pragma unroll
                            for (int rt = 0; rt < 2; ++rt)
                                acc[rt][g][cc] = __builtin_amdgcn_mfma_f32_16x16x32_bf16(af[rt], bf, acc[rt][g][cc], 0, 0, 0);
                        }
                    __syncthreads();
                }
            }
        }
        // cell update (gates in registers; gX2 gives i,f,g,o as one 8-B load)
#pragma unroll
        for (int rt = 0; rt < 2; ++rt)
#pragma unroll
            for (int cc = 0; cc < 4; ++cc) {
                int hf = cc >> 1, c2 = cc & 1;
                int col = hf * 128 + wh * 32 + c2 * 16 + m;
#pragma unroll
                for (int r2 = 0; r2 < 4; ++r2) {
                    int row = rt * 16 + q * 4 + r2;
                    vus4 gv = *(const vus4*)(gX + ((size_t)row * 256 + col) * 4);
                    float iv = acc[rt][0][cc][r2] + b2f(gv[0]);
                    float fv = acc[rt][1][cc][r2] + b2f(gv[1]);
                    float gg = acc[rt][2][cc][r2] + b2f(gv[2]);
                    float ov = acc[rt][3][cc][r2] + b2f(gv[3]);
                    float cn = sigm(fv) * c[rt][cc][r2] + sigm(iv) * tanhf(gg);
                    c[rt][cc][r2] = cn;
                    sH[row * HP + col] = f2b(sigm(ov) * tanhf(cn));
                }
            }
        __syncthreads();
    }
    // write h_last to global [k][n][256]
    unsigned short* dst = hout + ((size_t)(k * NN_ + n0)) * 256;
#pragma unroll
    for (int it = 0; it < 4; ++it) {
        int e = it * 256 + t, row = e >> 5, c8 = (e & 31) << 3;
        *(vu4*)(dst + (size_t)row * 256 + c8) = *(const vu4*)(&sH[row * HP + c8]);
    }
}

// ---------------------------------------------------------------------------
// final_ep: pred = sig_slice(x + mean_k delta); res[n][f][k] = sig_slice(x + delta_k)
// ---------------------------------------------------------------------------
__global__ __launch_bounds__(256) void final_ep(const float* __restrict__ x,
        const unsigned short* __restrict__ delta, float* __restrict__ pred,
        float* __restrict__ res) {
    int idx = blockIdx.x * 256 + threadIdx.x;
    size_t base = (size_t)idx * 8;
    int f0 = (int)(base & 255);
    alignas(16) unsigned short d0[8], d1[8], d2[8];
    alignas(16) float pr[8], rs[24];
    vf4 xa = *(const vf4*)(x + base), xb = *(const vf4*)(x + base + 4);
    float xs[8] = { xa[0], xa[1], xa[2], xa[3], xb[0], xb[1], xb[2], xb[3] };
    *(vu4*)d0 = *(const vu4*)(delta + base);
    *(vu4*)d1 = *(const vu4*)(delta + (size_t)NN_ * FD + base);
    *(vu4*)d2 = *(const vu4*)(delta + 2 * (size_t)NN_ * FD + base);
#pragma unroll
    for (int e = 0; e < 8; ++e) {
        int f = f0 + e;
        bool sg = (f >= 10) && (f < 253);
        float xf = xs[e];
        float da = b2f(d0[e]), db = b2f(d1[e]), dc = b2f(d2[e]);
        float dm = (da + db + dc) * (1.f / 3.f);
        float p = xf + dm; if (sg) p = sigm(p);
        pr[e] = p;
        float z0 = xf + da; if (sg) z0 = sigm(z0);
        float z1 = xf + db; if (sg) z1 = sigm(z1);
        float z2 = xf + dc; if (sg) z2 = sigm(z2);
        rs[e * 3 + 0] = z0; rs[e * 3 + 1] = z1; rs[e * 3 + 2] = z2;
    }
    *(vf4*)(pred + base)     = *(vf4*)pr;
    *(vf4*)(pred + base + 4) = *(vf4*)(pr + 4);
    size_t rb = base * 3;
#pragma unroll
    for (int v = 0; v < 6; ++v)
        *(vf4*)(res + rb + v * 4) = *(vf4*)(rs + v * 4);
}

extern "C" void kernel_launch(void* const* d_in, const int* in_sizes, int n_in,
                              void* d_out, int out_size, void* d_ws, size_t ws_size,
                              hipStream_t stream) {
    const float* x    = (const float*)d_in[0];
    const float* gnnw = (const float*)d_in[1];
    const float* gnnb = (const float*)d_in[2];
    const float* wih  = (const float*)d_in[3];
    const float* whh  = (const float*)d_in[4];
    const float* bih  = (const float*)d_in[5];
    const float* bhh  = (const float*)d_in[6];
    const float* fcw  = (const float*)d_in[7];
    const float* fcb  = (const float*)d_in[8];
    const int*   adj  = (const int*)d_in[9];

    float* out = (float*)d_out;
    float* out_pred = out;
    float* out_res  = out + (size_t)NN_ * FD;
    float* out_adj  = out + (size_t)NN_ * FD * 4;

    // ws layout (~142 MB; poison-fill evidence says ws is ~650+ MB):
    //   dinv | R1 (yT -> h_last) | R2 (xt -> delta) | wb | pbuf/gX2 | abk
    char* ws = (char*)d_ws;
    float*          dinv  = (float*)ws;                          // 49,152
    unsigned short* R1    = (unsigned short*)(ws + 49152);       // 6,291,456
    unsigned short* R2    = (unsigned short*)(ws + 6340608);     // 6,291,456
    unsigned short* wb    = (unsigned short*)(ws + 12632064);    // 3,538,944
    unsigned short* pbuf  = (unsigned short*)(ws + 16171008);    // 25,165,824
    unsigned short* gX2   = pbuf;                                // later lifetime
    unsigned short* abk   = (unsigned short*)(ws + 41336832);    // 100,663,296 -> 142,000,128
    const unsigned short* wihb = wb;
    const unsigned short* whhb = wb + 786432;
    const unsigned short* fcwb = wb + 1572864;
    (void)ws_size; (void)in_sizes; (void)n_in; (void)out_size;

    wcvt<<<dim3(864), 256, 0, stream>>>(wih, whh, fcw, wb);
    adj_pass<<<dim3(4096), 256, 0, stream>>>(adj, out_adj, abk, dinv);
    gemm_xw<<<dim3(64, 4, 3), 256, 0, stream>>>(x, gnnw, dinv, R1 /*yT*/);
    gemm_agg<<<dim3(2, 64, 4), 256, 0, stream>>>(abk, R1 /*yT*/, pbuf);
    agg_reduce<<<dim3(1536), 256, 0, stream>>>(pbuf, dinv, gnnb, R2 /*xt*/);
    gemm_nt_ep<<<dim3(16, 64, 3), 256, 0, stream>>>(R2 /*xt*/, wihb, bih, bhh, gX2, GD, 0, 1);
    lstm_fused<<<dim3(128, 3), 256, 0, stream>>>(gX2, whhb, R1 /*h_last*/);
    gemm_nt_ep<<<dim3(4, 64, 3), 256, 0, stream>>>(R1, fcwb, fcb, nullptr, R2 /*delta*/, FD, 1, 0);
    final_ep<<<dim3(512), 256, 0, stream>>>(x, R2 /*delta*/, out_pred, out_res);
}

// Round 7
// 749.402 us; speedup vs baseline: 1.2653x; 1.2653x over previous
//
#include <hip/hip_runtime.h>
#include <stdint.h>

// MGMCGCN — 3x (binary-GCN + 5-step LSTM + fc/tanh).
// Dtypes: float inputs f32, adj int32, ALL OUTPUTS f32. Internal bf16 MFMA.
// N=4096, F=H=256, K=3, T=5, G=4H=1024.
#define NN_ 4096
#define FD 256
#define HD 256
#define KC 3
#define GD 1024
#define SA 40    // padded LDS pitch (shorts): 80 B row stride
#define PAG 40

typedef __attribute__((ext_vector_type(4))) unsigned int vu4;     // 16 B
typedef __attribute__((ext_vector_type(4))) int vi4;              // 16 B
typedef __attribute__((ext_vector_type(4))) float vf4;            // 16 B
typedef __attribute__((ext_vector_type(4))) unsigned short vus4;  // 8 B
typedef __attribute__((ext_vector_type(8))) short short8;         // bf16x8 MFMA frag
typedef __attribute__((ext_vector_type(4))) float f32x4;          // MFMA acc

__device__ __forceinline__ float b2f(unsigned short u) {
    unsigned int v = ((unsigned int)u) << 16; float f; __builtin_memcpy(&f, &v, 4); return f;
}
__device__ __forceinline__ unsigned short f2b(float x) {
    unsigned int u; __builtin_memcpy(&u, &x, 4);
    u = (u + 0x7FFFu + ((u >> 16) & 1u)) >> 16;   // RNE
    return (unsigned short)u;
}
__device__ __forceinline__ void cvt8(const float* __restrict__ g, unsigned short* o) {
    vf4 a = *(const vf4*)g, b = *(const vf4*)(g + 4);
    o[0] = f2b(a[0]); o[1] = f2b(a[1]); o[2] = f2b(a[2]); o[3] = f2b(a[3]);
    o[4] = f2b(b[0]); o[5] = f2b(b[1]); o[6] = f2b(b[2]); o[7] = f2b(b[3]);
}
__device__ __forceinline__ float sigm(float v) { return 1.f / (1.f + __expf(-v)); }

// ---------------------------------------------------------------------------
// adj_pass: read adj int32 [N][N][K]; write (a) f32 0/1 interleaved copy to the
// d_out adj region, (b) bf16 deinterleaved planes abk[k][i][j] for gemm_agg;
// compute dinv[k][i].
// ---------------------------------------------------------------------------
__global__ __launch_bounds__(256) void adj_pass(const int* __restrict__ adj,
        float* __restrict__ adj_out, unsigned short* __restrict__ abk,
        float* __restrict__ dinv) {
    const int i = blockIdx.x, t = threadIdx.x;
    const int* src = adj + (size_t)i * 12288;
    float* dstf = adj_out + (size_t)i * 12288;
    float s0 = 0.f, s1 = 0.f, s2 = 0.f;
#pragma unroll
    for (int it = 0; it < 4; ++it) {
        int jq = (it * 256 + t) * 4;
        vi4 a = *(const vi4*)(src + jq * 3);
        vi4 b = *(const vi4*)(src + jq * 3 + 4);
        vi4 c = *(const vi4*)(src + jq * 3 + 8);
        int vv[12] = {a[0],a[1],a[2],a[3],b[0],b[1],b[2],b[3],c[0],c[1],c[2],c[3]};
        float ff[12];
#pragma unroll
        for (int e = 0; e < 12; ++e) ff[e] = vv[e] ? 1.f : 0.f;
        vf4 w0 = {ff[0],ff[1],ff[2],ff[3]}, w1 = {ff[4],ff[5],ff[6],ff[7]}, w2 = {ff[8],ff[9],ff[10],ff[11]};
        *(vf4*)(dstf + jq * 3) = w0; *(vf4*)(dstf + jq * 3 + 4) = w1; *(vf4*)(dstf + jq * 3 + 8) = w2;
#pragma unroll
        for (int k = 0; k < 3; ++k) {
            vus4 w;
            w[0] = vv[k]     ? (unsigned short)0x3F80 : (unsigned short)0;
            w[1] = vv[3 + k] ? (unsigned short)0x3F80 : (unsigned short)0;
            w[2] = vv[6 + k] ? (unsigned short)0x3F80 : (unsigned short)0;
            w[3] = vv[9 + k] ? (unsigned short)0x3F80 : (unsigned short)0;
            *(vus4*)(abk + ((size_t)(k * NN_ + i)) * NN_ + jq) = w;
        }
        s0 += ff[0] + ff[3] + ff[6] + ff[9];
        s1 += ff[1] + ff[4] + ff[7] + ff[10];
        s2 += ff[2] + ff[5] + ff[8] + ff[11];
    }
    __shared__ float r0[256], r1[256], r2[256];
    r0[t] = s0; r1[t] = s1; r2[t] = s2;
    __syncthreads();
    for (int off = 128; off > 0; off >>= 1) {
        if (t < off) { r0[t] += r0[t + off]; r1[t] += r1[t + off]; r2[t] += r2[t + off]; }
        __syncthreads();
    }
    if (t == 0) {
        dinv[i]            = 1.f / sqrtf(1.f + r0[0]);
        dinv[NN_ + i]      = 1.f / sqrtf(1.f + r1[0]);
        dinv[2 * NN_ + i]  = 1.f / sqrtf(1.f + r2[0]);
    }
}

// ---------------------------------------------------------------------------
// wcvt: one-time f32->bf16 of [wih | whh | fcw] into contiguous wb.
// ---------------------------------------------------------------------------
__global__ __launch_bounds__(256) void wcvt(const float* __restrict__ wih,
        const float* __restrict__ whh, const float* __restrict__ fcw,
        unsigned short* __restrict__ wb) {
    size_t e = ((size_t)blockIdx.x * 256 + threadIdx.x) * 8;
    const float* src; size_t off;
    if (e < 786432)       { src = wih; off = e; }
    else if (e < 1572864) { src = whh; off = e - 786432; }
    else                  { src = fcw; off = e - 1572864; }
    alignas(16) unsigned short o[8];
    cvt8(src + off, o);
    *(vu4*)(wb + e) = *(vu4*)o;
}

// ---------------------------------------------------------------------------
// GEMM1: yT[k][h][j] = dinv[k][j] * (x @ gnn_w[k])[j][h] (transposed store).
// ---------------------------------------------------------------------------
__global__ __launch_bounds__(256) void gemm_xw(const float* __restrict__ x,
        const float* __restrict__ gw, const float* __restrict__ dinv,
        unsigned short* __restrict__ yT) {
    __shared__ __align__(16) unsigned short sA[64 * SA], sB[64 * SA];
    const int bi = blockIdx.x, bj = blockIdx.y, k = blockIdx.z;
    const int t = threadIdx.x, lane = t & 63, wave = t >> 6;
    const int m = lane & 15, q = lane >> 4, ko = q * 8;
    const int h0 = bj * 64;
    f32x4 acc[4] = {};
    const float* A0 = x + (size_t)(bi * 64) * FD;
    const float* B0 = gw + (size_t)k * FD * HD;
    const int r = t >> 2, c8 = (t & 3) << 3;
    const int fB = t >> 3, c8B = (t & 7) << 3;
    for (int k0 = 0; k0 < FD; k0 += 32) {
        alignas(16) unsigned short tA[8], tB[8];
        cvt8(A0 + (size_t)r * FD + k0 + c8, tA);
        *(vu4*)(sA + r * SA + c8) = *(vu4*)tA;
        cvt8(B0 + (size_t)(k0 + fB) * HD + h0 + c8B, tB);
#pragma unroll
        for (int e = 0; e < 8; ++e) sB[(c8B + e) * SA + fB] = tB[e];
        __syncthreads();
        short8 af = *(const short8*)(sA + (wave * 16 + m) * SA + ko);
#pragma unroll
        for (int ct = 0; ct < 4; ++ct) {
            short8 bf = *(const short8*)(sB + (ct * 16 + m) * SA + ko);
            acc[ct] = __builtin_amdgcn_mfma_f32_16x16x32_bf16(af, bf, acc[ct], 0, 0, 0);
        }
        __syncthreads();
    }
    unsigned short* yTk = yT + (size_t)k * HD * NN_;
#pragma unroll
    for (int ct = 0; ct < 4; ++ct)
#pragma unroll
        for (int r2 = 0; r2 < 4; ++r2) {
            int col = h0 + ct * 16 + m;
            int row = bi * 64 + wave * 16 + q * 4 + r2;
            yTk[(size_t)col * NN_ + row] = f2b(acc[ct][r2] * dinv[(size_t)k * NN_ + row]);
        }
}

// ---------------------------------------------------------------------------
// GEMM2 (j-split): pbuf[s][k][i][h] = sum_{j in chunk s} A_k[i][j]*y_k[j][h]
//   (+ self y_k[i][h] in the chunk containing j==i). A = bf16 planes abk.
// Block 64i x 128h x 1024j, waves 2x2, grid (2,64,4)=512.
// ---------------------------------------------------------------------------
__global__ __launch_bounds__(256) void gemm_agg(const unsigned short* __restrict__ abk,
        const unsigned short* __restrict__ yT, unsigned short* __restrict__ pbuf) {
    __shared__ __align__(16) unsigned short sA[3][64 * PAG];
    __shared__ __align__(16) unsigned short sB[3][128 * PAG];
    const int bh = blockIdx.x, bi = blockIdx.y, s = blockIdx.z;
    const int t = threadIdx.x, lane = t & 63, wave = t >> 6;
    const int wi = wave & 1, wh = wave >> 1;
    const int m = lane & 15, q = lane >> 4, ko = q * 8;
    const int i0 = bi * 64, h0 = bh * 128, jbase = s * 1024;
    f32x4 acc[3][2][4] = {};
    const int rA = t >> 2, jg = (t & 3) << 3;
    for (int j0 = 0; j0 < 1024; j0 += 32) {
#pragma unroll
        for (int p = 0; p < 3; ++p)
            *(vu4*)(&sA[p][rA * PAG + jg]) =
                *(const vu4*)(abk + ((size_t)(p * NN_ + i0 + rA)) * NN_ + jbase + j0 + jg);
#pragma unroll
        for (int it = 0; it < 6; ++it) {
            int e = it * 256 + t, k = e >> 9, r = (e & 511) >> 2, c = (e & 3) << 3;
            *(vu4*)(&sB[k][r * PAG + c]) =
                *(const vu4*)(yT + (size_t)(k * 256 + h0 + r) * 4096 + jbase + j0 + c);
        }
        __syncthreads();
        short8 aF[3][2];
#pragma unroll
        for (int k = 0; k < 3; ++k)
#pragma unroll
            for (int rt = 0; rt < 2; ++rt)
                aF[k][rt] = *(const short8*)(&sA[k][(wi * 32 + rt * 16 + m) * PAG + ko]);
#pragma unroll
        for (int k = 0; k < 3; ++k)
#pragma unroll
            for (int ct = 0; ct < 4; ++ct) {
                short8 bF = *(const short8*)(&sB[k][(wh * 64 + ct * 16 + m) * PAG + ko]);
#pragma unroll
                for (int rt = 0; rt < 2; ++rt)
                    acc[k][rt][ct] = __builtin_amdgcn_mfma_f32_16x16x32_bf16(aF[k][rt], bF, acc[k][rt][ct], 0, 0, 0);
            }
        __syncthreads();
    }
    const int addself = (s == (i0 >> 10));
#pragma unroll
    for (int k = 0; k < 3; ++k)
#pragma unroll
        for (int rt = 0; rt < 2; ++rt)
#pragma unroll
            for (int ct = 0; ct < 4; ++ct)
#pragma unroll
                for (int r2 = 0; r2 < 4; ++r2) {
                    int row = i0 + wi * 32 + rt * 16 + q * 4 + r2;
                    int col = h0 + wh * 64 + ct * 16 + m;
                    float v = acc[k][rt][ct][r2];
                    if (addself) v += b2f(yT[((size_t)k * 256 + col) * 4096 + row]);
                    pbuf[(((size_t)s * 3 + k) * 4096 + row) * 256 + col] = f2b(v);
                }
}

// ---------------------------------------------------------------------------
// agg_reduce: xt[k][i][h] = f2b(dinv[k][i] * (sum_s pbuf[s]) + gnnb[k][h])
// ---------------------------------------------------------------------------
__global__ __launch_bounds__(256) void agg_reduce(const unsigned short* __restrict__ pbuf,
        const float* __restrict__ dinv, const float* __restrict__ gnnb,
        unsigned short* __restrict__ xt) {
    size_t e8 = ((size_t)blockIdx.x * 256 + threadIdx.x) * 8;
    int k = (int)(e8 >> 20);
    int i = (int)((e8 >> 8) & 4095);
    int h = (int)(e8 & 255);
    float di = dinv[k * NN_ + i];
    const size_t KIH = (size_t)KC * NN_ * HD;
    alignas(16) unsigned short p0[8], p1[8], p2[8], p3[8], o[8];
    *(vu4*)p0 = *(const vu4*)(pbuf + 0 * KIH + e8);
    *(vu4*)p1 = *(const vu4*)(pbuf + 1 * KIH + e8);
    *(vu4*)p2 = *(const vu4*)(pbuf + 2 * KIH + e8);
    *(vu4*)p3 = *(const vu4*)(pbuf + 3 * KIH + e8);
#pragma unroll
    for (int e = 0; e < 8; ++e) {
        float v = b2f(p0[e]) + b2f(p1[e]) + b2f(p2[e]) + b2f(p3[e]);
        o[e] = f2b(di * v + gnnb[k * HD + h + e]);
    }
    *(vu4*)(xt + e8) = *(vu4*)o;
}

// ---------------------------------------------------------------------------
// lstm_gemm: 128x128-tile NT GEMM, M=12288 (3k batched), N=1024, K=256.
// out (gate-interleaved): out[grow][ch][4] = A[grow][:] . W[kk][col][:] (+b1+b2)
// where col = gate*256+ch. Used for gateX (A=xt, W=wih, b=bih+bhh) and each
// LSTM step (A=h, W=whh, no bias). 2x2 waves, acc[4][4] (64 VGPR, no spill).
// ---------------------------------------------------------------------------
__global__ __launch_bounds__(256) void lstm_gemm(const unsigned short* __restrict__ A,
        const unsigned short* __restrict__ W, const float* __restrict__ b1,
        const float* __restrict__ b2, unsigned short* __restrict__ outp) {
    __shared__ __align__(16) unsigned short sA[128 * SA], sB[128 * SA];
    const int bg = blockIdx.x, bn = blockIdx.y;   // bg<8 (128 cols), bn<96 (128 rows)
    const int t = threadIdx.x, lane = t & 63, wave = t >> 6;
    const int wi = wave & 1, wh = wave >> 1;
    const int m = lane & 15, q = lane >> 4, ko = q * 8;
    const int kk = bn >> 5;
    f32x4 acc[4][4] = {};
    const unsigned short* A0 = A + (size_t)bn * 128 * 256;
    const unsigned short* W0 = W + ((size_t)kk * 1024 + bg * 128) * 256;
    const int r = t >> 1, cA = (t & 1) << 4;      // 128 rows x 32 cols, 2 thr/row
    for (int k0 = 0; k0 < 256; k0 += 32) {
        *(vu4*)(sA + r * SA + cA)     = *(const vu4*)(A0 + (size_t)r * 256 + k0 + cA);
        *(vu4*)(sA + r * SA + cA + 8) = *(const vu4*)(A0 + (size_t)r * 256 + k0 + cA + 8);
        *(vu4*)(sB + r * SA + cA)     = *(const vu4*)(W0 + (size_t)r * 256 + k0 + cA);
        *(vu4*)(sB + r * SA + cA + 8) = *(const vu4*)(W0 + (size_t)r * 256 + k0 + cA + 8);
        __syncthreads();
        short8 af[4], bf[4];
#pragma unroll
        for (int rt = 0; rt < 4; ++rt)
            af[rt] = *(const short8*)(sA + (wi * 64 + rt * 16 + m) * SA + ko);
#pragma unroll
        for (int ct = 0; ct < 4; ++ct)
            bf[ct] = *(const short8*)(sB + (wh * 64 + ct * 16 + m) * SA + ko);
#pragma unroll
        for (int ct = 0; ct < 4; ++ct)
#pragma unroll
            for (int rt = 0; rt < 4; ++rt)
                acc[rt][ct] = __builtin_amdgcn_mfma_f32_16x16x32_bf16(af[rt], bf[ct], acc[rt][ct], 0, 0, 0);
        __syncthreads();
    }
#pragma unroll
    for (int rt = 0; rt < 4; ++rt)
#pragma unroll
        for (int ct = 0; ct < 4; ++ct)
#pragma unroll
            for (int r2 = 0; r2 < 4; ++r2) {
                int grow = bn * 128 + wi * 64 + rt * 16 + q * 4 + r2;   // 0..12287
                int cp = bg * 128 + wh * 64 + ct * 16 + m;              // 0..1023
                float v = acc[rt][ct][r2];
                if (b1) v += b1[kk * 1024 + cp];
                if (b2) v += b2[kk * 1024 + cp];
                int gate = cp >> 8, ch = cp & 255;
                outp[((size_t)grow * 256 + ch) * 4 + gate] = f2b(v);
            }
}

// ---------------------------------------------------------------------------
// lstm_cell: elementwise over [3][4096][256]. g = gacc + gX (both gate-ilv
// [row][ch][4]); c = sig(f)*c + sig(i)*tanh(g); h = sig(o)*tanh(c).
// first=1: gacc ignored (h0=0), c initialized.
// ---------------------------------------------------------------------------
__global__ __launch_bounds__(256) void lstm_cell(const unsigned short* __restrict__ gacc,
        const unsigned short* __restrict__ gX2, float* __restrict__ cbuf,
        unsigned short* __restrict__ hbuf, int first) {
    size_t e8 = ((size_t)blockIdx.x * 256 + threadIdx.x) * 8;   // 8 ch per thread
    size_t gb = e8 * 4;                                          // ilv offset (32 shorts)
    alignas(16) unsigned short gx[32], ga[32];
    *(vu4*)(gx)      = *(const vu4*)(gX2 + gb);
    *(vu4*)(gx + 8)  = *(const vu4*)(gX2 + gb + 8);
    *(vu4*)(gx + 16) = *(const vu4*)(gX2 + gb + 16);
    *(vu4*)(gx + 24) = *(const vu4*)(gX2 + gb + 24);
    if (!first) {
        *(vu4*)(ga)      = *(const vu4*)(gacc + gb);
        *(vu4*)(ga + 8)  = *(const vu4*)(gacc + gb + 8);
        *(vu4*)(ga + 16) = *(const vu4*)(gacc + gb + 16);
        *(vu4*)(ga + 24) = *(const vu4*)(gacc + gb + 24);
    }
    alignas(16) float cv[8];
    if (!first) {
        *(vf4*)cv       = *(const vf4*)(cbuf + e8);
        *(vf4*)(cv + 4) = *(const vf4*)(cbuf + e8 + 4);
    }
    alignas(16) unsigned short h8[8];
#pragma unroll
    for (int e = 0; e < 8; ++e) {
        float iv = b2f(gx[e * 4 + 0]), fv = b2f(gx[e * 4 + 1]);
        float gg = b2f(gx[e * 4 + 2]), ov = b2f(gx[e * 4 + 3]);
        if (!first) {
            iv += b2f(ga[e * 4 + 0]); fv += b2f(ga[e * 4 + 1]);
            gg += b2f(ga[e * 4 + 2]); ov += b2f(ga[e * 4 + 3]);
        }
        float cold = first ? 0.f : cv[e];
        float cn = sigm(fv) * cold + sigm(iv) * tanhf(gg);
        cv[e] = cn;
        h8[e] = f2b(sigm(ov) * tanhf(cn));
    }
    *(vf4*)(cbuf + e8)     = *(vf4*)cv;
    *(vf4*)(cbuf + e8 + 4) = *(vf4*)(cv + 4);
    *(vu4*)(hbuf + e8) = *(vu4*)h8;
}

// ---------------------------------------------------------------------------
// NT GEMM (fc): out[k][n][col] = tanh(A . W^T + b1). 64x64 tiles.
// ---------------------------------------------------------------------------
__global__ __launch_bounds__(256) void gemm_nt_ep(const unsigned short* __restrict__ A,
        const unsigned short* __restrict__ W, const float* __restrict__ b1,
        unsigned short* __restrict__ outp, int COLS, int do_tanh) {
    __shared__ __align__(16) unsigned short sA[64 * SA], sB[64 * SA];
    const int bg = blockIdx.x, bn = blockIdx.y, k = blockIdx.z;
    const int t = threadIdx.x, lane = t & 63, wave = t >> 6;
    const int m = lane & 15, q = lane >> 4, ko = q * 8;
    f32x4 acc[4] = {};
    const unsigned short* A0 = A + ((size_t)k * NN_ + bn * 64) * HD;
    const unsigned short* W0 = W + ((size_t)k * COLS + bg * 64) * HD;
    const int r = t >> 2, c8 = (t & 3) << 3;
    for (int k0 = 0; k0 < HD; k0 += 32) {
        *(vu4*)(sA + r * SA + c8) = *(const vu4*)(A0 + (size_t)r * HD + k0 + c8);
        *(vu4*)(sB + r * SA + c8) = *(const vu4*)(W0 + (size_t)r * HD + k0 + c8);
        __syncthreads();
        short8 af = *(const short8*)(sA + (wave * 16 + m) * SA + ko);
#pragma unroll
        for (int ct = 0; ct < 4; ++ct) {
            short8 bf = *(const short8*)(sB + (ct * 16 + m) * SA + ko);
            acc[ct] = __builtin_amdgcn_mfma_f32_16x16x32_bf16(af, bf, acc[ct], 0, 0, 0);
        }
        __syncthreads();
    }
#pragma unroll
    for (int ct = 0; ct < 4; ++ct)
#pragma unroll
        for (int r2 = 0; r2 < 4; ++r2) {
            int col = bg * 64 + ct * 16 + m;
            int row = bn * 64 + wave * 16 + q * 4 + r2;
            float v = acc[ct][r2];
            if (b1) v += b1[(size_t)k * COLS + col];
            if (do_tanh) v = tanhf(v);
            outp[((size_t)k * NN_ + row) * COLS + col] = f2b(v);
        }
}

// ---------------------------------------------------------------------------
// final_ep: pred = sig_slice(x + mean_k delta); res[n][f][k] = sig_slice(x + delta_k)
// ---------------------------------------------------------------------------
__global__ __launch_bounds__(256) void final_ep(const float* __restrict__ x,
        const unsigned short* __restrict__ delta, float* __restrict__ pred,
        float* __restrict__ res) {
    int idx = blockIdx.x * 256 + threadIdx.x;
    size_t base = (size_t)idx * 8;
    int f0 = (int)(base & 255);
    alignas(16) unsigned short d0[8], d1[8], d2[8];
    alignas(16) float pr[8], rs[24];
    vf4 xa = *(const vf4*)(x + base), xb = *(const vf4*)(x + base + 4);
    float xs[8] = { xa[0], xa[1], xa[2], xa[3], xb[0], xb[1], xb[2], xb[3] };
    *(vu4*)d0 = *(const vu4*)(delta + base);
    *(vu4*)d1 = *(const vu4*)(delta + (size_t)NN_ * FD + base);
    *(vu4*)d2 = *(const vu4*)(delta + 2 * (size_t)NN_ * FD + base);
#pragma unroll
    for (int e = 0; e < 8; ++e) {
        int f = f0 + e;
        bool sg = (f >= 10) && (f < 253);
        float xf = xs[e];
        float da = b2f(d0[e]), db = b2f(d1[e]), dc = b2f(d2[e]);
        float dm = (da + db + dc) * (1.f / 3.f);
        float p = xf + dm; if (sg) p = sigm(p);
        pr[e] = p;
        float z0 = xf + da; if (sg) z0 = sigm(z0);
        float z1 = xf + db; if (sg) z1 = sigm(z1);
        float z2 = xf + dc; if (sg) z2 = sigm(z2);
        rs[e * 3 + 0] = z0; rs[e * 3 + 1] = z1; rs[e * 3 + 2] = z2;
    }
    *(vf4*)(pred + base)     = *(vf4*)pr;
    *(vf4*)(pred + base + 4) = *(vf4*)(pr + 4);
    size_t rb = base * 3;
#pragma unroll
    for (int v = 0; v < 6; ++v)
        *(vf4*)(res + rb + v * 4) = *(vf4*)(rs + v * 4);
}

extern "C" void kernel_launch(void* const* d_in, const int* in_sizes, int n_in,
                              void* d_out, int out_size, void* d_ws, size_t ws_size,
                              hipStream_t stream) {
    const float* x    = (const float*)d_in[0];
    const float* gnnw = (const float*)d_in[1];
    const float* gnnb = (const float*)d_in[2];
    const float* wih  = (const float*)d_in[3];
    const float* whh  = (const float*)d_in[4];
    const float* bih  = (const float*)d_in[5];
    const float* bhh  = (const float*)d_in[6];
    const float* fcw  = (const float*)d_in[7];
    const float* fcb  = (const float*)d_in[8];
    const int*   adj  = (const int*)d_in[9];

    float* out = (float*)d_out;
    float* out_pred = out;
    float* out_res  = out + (size_t)NN_ * FD;
    float* out_adj  = out + (size_t)NN_ * FD * 4;

    // ws layout (~180 MB; ws is ~650+ MB per poison-fill evidence):
    char* ws = (char*)d_ws;
    float*          dinv  = (float*)ws;                          // 49,152
    unsigned short* R1    = (unsigned short*)(ws + 49152);       // 6,291,456 (yT -> h)
    unsigned short* R2    = (unsigned short*)(ws + 6340608);     // 6,291,456 (xt -> delta)
    unsigned short* wb    = (unsigned short*)(ws + 12632064);    // 3,538,944
    unsigned short* pbuf  = (unsigned short*)(ws + 16171008);    // 25,165,824
    unsigned short* gX2   = pbuf;                                // later lifetime
    unsigned short* abk   = (unsigned short*)(ws + 41336832);    // 100,663,296
    unsigned short* gacc  = (unsigned short*)(ws + 142000128);   // 25,165,824
    float*          cbuf  = (float*)(ws + 167165952);            // 12,582,912 -> 179,748,864
    const unsigned short* wihb = wb;
    const unsigned short* whhb = wb + 786432;
    const unsigned short* fcwb = wb + 1572864;
    (void)ws_size; (void)in_sizes; (void)n_in; (void)out_size;

    wcvt<<<dim3(864), 256, 0, stream>>>(wih, whh, fcw, wb);
    adj_pass<<<dim3(4096), 256, 0, stream>>>(adj, out_adj, abk, dinv);
    gemm_xw<<<dim3(64, 4, 3), 256, 0, stream>>>(x, gnnw, dinv, R1 /*yT*/);
    gemm_agg<<<dim3(2, 64, 4), 256, 0, stream>>>(abk, R1 /*yT*/, pbuf);
    agg_reduce<<<dim3(1536), 256, 0, stream>>>(pbuf, dinv, gnnb, R2 /*xt*/);
    lstm_gemm<<<dim3(8, 96), 256, 0, stream>>>(R2 /*xt*/, wihb, bih, bhh, gX2);
    lstm_cell<<<dim3(1536), 256, 0, stream>>>(gacc, gX2, cbuf, R1 /*h*/, 1);
    for (int tstep = 1; tstep < 5; ++tstep) {
        lstm_gemm<<<dim3(8, 96), 256, 0, stream>>>(R1 /*h*/, whhb, nullptr, nullptr, gacc);
        lstm_cell<<<dim3(1536), 256, 0, stream>>>(gacc, gX2, cbuf, R1 /*h*/, 0);
    }
    gemm_nt_ep<<<dim3(4, 64, 3), 256, 0, stream>>>(R1 /*h_last*/, fcwb, fcb, R2 /*delta*/, FD, 1);
    final_ep<<<dim3(512), 256, 0, stream>>>(x, R2 /*delta*/, out_pred, out_res);
}

// Round 8
// 642.118 us; speedup vs baseline: 1.4767x; 1.1671x over previous
//
#include <hip/hip_runtime.h>
#include <stdint.h>

// MGMCGCN — 3x (binary-GCN + 5-step LSTM + fc/tanh).
// Dtypes: float inputs f32, adj int32, ALL OUTPUTS f32. Internal bf16 MFMA.
// N=4096, F=H=256, K=3, T=5, G=4H=1024.
#define NN_ 4096
#define FD 256
#define HD 256
#define KC 3
#define GD 1024
#define SA 40    // padded LDS pitch (shorts): 80 B row stride
#define PAG 40

typedef __attribute__((ext_vector_type(4))) unsigned int vu4;     // 16 B
typedef __attribute__((ext_vector_type(4))) int vi4;              // 16 B
typedef __attribute__((ext_vector_type(4))) float vf4;            // 16 B
typedef __attribute__((ext_vector_type(4))) unsigned short vus4;  // 8 B
typedef __attribute__((ext_vector_type(8))) short short8;         // bf16x8 MFMA frag
typedef __attribute__((ext_vector_type(4))) float f32x4;          // MFMA acc

__device__ __forceinline__ float b2f(unsigned short u) {
    unsigned int v = ((unsigned int)u) << 16; float f; __builtin_memcpy(&f, &v, 4); return f;
}
__device__ __forceinline__ unsigned short f2b(float x) {
    unsigned int u; __builtin_memcpy(&u, &x, 4);
    u = (u + 0x7FFFu + ((u >> 16) & 1u)) >> 16;   // RNE
    return (unsigned short)u;
}
__device__ __forceinline__ void cvt8(const float* __restrict__ g, unsigned short* o) {
    vf4 a = *(const vf4*)g, b = *(const vf4*)(g + 4);
    o[0] = f2b(a[0]); o[1] = f2b(a[1]); o[2] = f2b(a[2]); o[3] = f2b(a[3]);
    o[4] = f2b(b[0]); o[5] = f2b(b[1]); o[6] = f2b(b[2]); o[7] = f2b(b[3]);
}
__device__ __forceinline__ float sigm(float v) { return 1.f / (1.f + __expf(-v)); }

// ---------------------------------------------------------------------------
// adj_pass: read adj int32 [N][N][K]; write (a) f32 0/1 interleaved copy to the
// d_out adj region, (b) bf16 deinterleaved planes abk[k][i][j]; compute dinv.
// ---------------------------------------------------------------------------
__global__ __launch_bounds__(256) void adj_pass(const int* __restrict__ adj,
        float* __restrict__ adj_out, unsigned short* __restrict__ abk,
        float* __restrict__ dinv) {
    const int i = blockIdx.x, t = threadIdx.x;
    const int* src = adj + (size_t)i * 12288;
    float* dstf = adj_out + (size_t)i * 12288;
    float s0 = 0.f, s1 = 0.f, s2 = 0.f;
#pragma unroll
    for (int it = 0; it < 4; ++it) {
        int jq = (it * 256 + t) * 4;
        vi4 a = *(const vi4*)(src + jq * 3);
        vi4 b = *(const vi4*)(src + jq * 3 + 4);
        vi4 c = *(const vi4*)(src + jq * 3 + 8);
        int vv[12] = {a[0],a[1],a[2],a[3],b[0],b[1],b[2],b[3],c[0],c[1],c[2],c[3]};
        float ff[12];
#pragma unroll
        for (int e = 0; e < 12; ++e) ff[e] = vv[e] ? 1.f : 0.f;
        vf4 w0 = {ff[0],ff[1],ff[2],ff[3]}, w1 = {ff[4],ff[5],ff[6],ff[7]}, w2 = {ff[8],ff[9],ff[10],ff[11]};
        *(vf4*)(dstf + jq * 3) = w0; *(vf4*)(dstf + jq * 3 + 4) = w1; *(vf4*)(dstf + jq * 3 + 8) = w2;
#pragma unroll
        for (int k = 0; k < 3; ++k) {
            vus4 w;
            w[0] = vv[k]     ? (unsigned short)0x3F80 : (unsigned short)0;
            w[1] = vv[3 + k] ? (unsigned short)0x3F80 : (unsigned short)0;
            w[2] = vv[6 + k] ? (unsigned short)0x3F80 : (unsigned short)0;
            w[3] = vv[9 + k] ? (unsigned short)0x3F80 : (unsigned short)0;
            *(vus4*)(abk + ((size_t)(k * NN_ + i)) * NN_ + jq) = w;
        }
        s0 += ff[0] + ff[3] + ff[6] + ff[9];
        s1 += ff[1] + ff[4] + ff[7] + ff[10];
        s2 += ff[2] + ff[5] + ff[8] + ff[11];
    }
    __shared__ float r0[256], r1[256], r2[256];
    r0[t] = s0; r1[t] = s1; r2[t] = s2;
    __syncthreads();
    for (int off = 128; off > 0; off >>= 1) {
        if (t < off) { r0[t] += r0[t + off]; r1[t] += r1[t + off]; r2[t] += r2[t + off]; }
        __syncthreads();
    }
    if (t == 0) {
        dinv[i]            = 1.f / sqrtf(1.f + r0[0]);
        dinv[NN_ + i]      = 1.f / sqrtf(1.f + r1[0]);
        dinv[2 * NN_ + i]  = 1.f / sqrtf(1.f + r2[0]);
    }
}

// ---------------------------------------------------------------------------
// wcvt: one-time f32->bf16 of [wih | whh | fcw] into contiguous wb.
// ---------------------------------------------------------------------------
__global__ __launch_bounds__(256) void wcvt(const float* __restrict__ wih,
        const float* __restrict__ whh, const float* __restrict__ fcw,
        unsigned short* __restrict__ wb) {
    size_t e = ((size_t)blockIdx.x * 256 + threadIdx.x) * 8;
    const float* src; size_t off;
    if (e < 786432)       { src = wih; off = e; }
    else if (e < 1572864) { src = whh; off = e - 786432; }
    else                  { src = fcw; off = e - 1572864; }
    alignas(16) unsigned short o[8];
    cvt8(src + off, o);
    *(vu4*)(wb + e) = *(vu4*)o;
}

// ---------------------------------------------------------------------------
// GEMM1: yT[k][h][j] = dinv[k][j] * (x @ gnn_w[k])[j][h] (transposed store).
// ---------------------------------------------------------------------------
__global__ __launch_bounds__(256) void gemm_xw(const float* __restrict__ x,
        const float* __restrict__ gw, const float* __restrict__ dinv,
        unsigned short* __restrict__ yT) {
    __shared__ __align__(16) unsigned short sA[64 * SA], sB[64 * SA];
    const int bi = blockIdx.x, bj = blockIdx.y, k = blockIdx.z;
    const int t = threadIdx.x, lane = t & 63, wave = t >> 6;
    const int m = lane & 15, q = lane >> 4, ko = q * 8;
    const int h0 = bj * 64;
    f32x4 acc[4] = {};
    const float* A0 = x + (size_t)(bi * 64) * FD;
    const float* B0 = gw + (size_t)k * FD * HD;
    const int r = t >> 2, c8 = (t & 3) << 3;
    const int fB = t >> 3, c8B = (t & 7) << 3;
    for (int k0 = 0; k0 < FD; k0 += 32) {
        alignas(16) unsigned short tA[8], tB[8];
        cvt8(A0 + (size_t)r * FD + k0 + c8, tA);
        *(vu4*)(sA + r * SA + c8) = *(vu4*)tA;
        cvt8(B0 + (size_t)(k0 + fB) * HD + h0 + c8B, tB);
#pragma unroll
        for (int e = 0; e < 8; ++e) sB[(c8B + e) * SA + fB] = tB[e];
        __syncthreads();
        short8 af = *(const short8*)(sA + (wave * 16 + m) * SA + ko);
#pragma unroll
        for (int ct = 0; ct < 4; ++ct) {
            short8 bf = *(const short8*)(sB + (ct * 16 + m) * SA + ko);
            acc[ct] = __builtin_amdgcn_mfma_f32_16x16x32_bf16(af, bf, acc[ct], 0, 0, 0);
        }
        __syncthreads();
    }
    unsigned short* yTk = yT + (size_t)k * HD * NN_;
#pragma unroll
    for (int ct = 0; ct < 4; ++ct)
#pragma unroll
        for (int r2 = 0; r2 < 4; ++r2) {
            int col = h0 + ct * 16 + m;
            int row = bi * 64 + wave * 16 + q * 4 + r2;
            yTk[(size_t)col * NN_ + row] = f2b(acc[ct][r2] * dinv[(size_t)k * NN_ + row]);
        }
}

// ---------------------------------------------------------------------------
// gemm_agg v3: per-k 128x128 tiles, 2x2 waves (wave 64x64, acc[4][4]), j-split
// s=4. pbuf[s][k][i][h] = sum_{j in s} abk_k[i][j]*yT_k[h][j] (+self).
// Grid (bh=2, bi=32, z=k*4+s) = 768 blocks. 8 ds_read_b128 per 16 MFMA.
// ---------------------------------------------------------------------------
__global__ __launch_bounds__(256) void gemm_agg(const unsigned short* __restrict__ abk,
        const unsigned short* __restrict__ yT, unsigned short* __restrict__ pbuf) {
    __shared__ __align__(16) unsigned short sA[128 * PAG], sB[128 * PAG];
    const int bh = blockIdx.x, bi = blockIdx.y, z = blockIdx.z;
    const int k = z >> 2, s = z & 3;
    const int t = threadIdx.x, lane = t & 63, wave = t >> 6;
    const int wi = wave & 1, wh = wave >> 1;
    const int m = lane & 15, q = lane >> 4, ko = q * 8;
    const int i0 = bi * 128, h0 = bh * 128, jbase = s * 1024;
    f32x4 acc[4][4] = {};
    const int r = t >> 1, cS = (t & 1) << 4;   // 128 rows x 32 j, 2 thr/row
    const unsigned short* Ab = abk + ((size_t)(k * NN_ + i0 + r)) * NN_ + jbase + cS;
    const unsigned short* Bb = yT + ((size_t)(k * 256 + h0 + r)) * NN_ + jbase + cS;
    for (int j0 = 0; j0 < 1024; j0 += 32) {
        *(vu4*)(sA + r * PAG + cS)     = *(const vu4*)(Ab + j0);
        *(vu4*)(sA + r * PAG + cS + 8) = *(const vu4*)(Ab + j0 + 8);
        *(vu4*)(sB + r * PAG + cS)     = *(const vu4*)(Bb + j0);
        *(vu4*)(sB + r * PAG + cS + 8) = *(const vu4*)(Bb + j0 + 8);
        __syncthreads();
        short8 af[4], bf[4];
#pragma unroll
        for (int rt = 0; rt < 4; ++rt)
            af[rt] = *(const short8*)(sA + (wi * 64 + rt * 16 + m) * PAG + ko);
#pragma unroll
        for (int ct = 0; ct < 4; ++ct)
            bf[ct] = *(const short8*)(sB + (wh * 64 + ct * 16 + m) * PAG + ko);
#pragma unroll
        for (int ct = 0; ct < 4; ++ct)
#pragma unroll
            for (int rt = 0; rt < 4; ++rt)
                acc[rt][ct] = __builtin_amdgcn_mfma_f32_16x16x32_bf16(af[rt], bf[ct], acc[rt][ct], 0, 0, 0);
        __syncthreads();
    }
    const int addself = ((bi >> 3) == s);   // 128-row block lies in one 1024-chunk
#pragma unroll
    for (int rt = 0; rt < 4; ++rt)
#pragma unroll
        for (int ct = 0; ct < 4; ++ct)
#pragma unroll
            for (int r2 = 0; r2 < 4; ++r2) {
                int row = i0 + wi * 64 + rt * 16 + q * 4 + r2;
                int col = h0 + wh * 64 + ct * 16 + m;
                float v = acc[rt][ct][r2];
                if (addself) v += b2f(yT[((size_t)k * 256 + col) * NN_ + row]);
                pbuf[(((size_t)s * 3 + k) * NN_ + row) * 256 + col] = f2b(v);
            }
}

// ---------------------------------------------------------------------------
// agg_reduce: xt[k][i][h] = f2b(dinv[k][i] * (sum_s pbuf[s]) + gnnb[k][h])
// ---------------------------------------------------------------------------
__global__ __launch_bounds__(256) void agg_reduce(const unsigned short* __restrict__ pbuf,
        const float* __restrict__ dinv, const float* __restrict__ gnnb,
        unsigned short* __restrict__ xt) {
    size_t e8 = ((size_t)blockIdx.x * 256 + threadIdx.x) * 8;
    int k = (int)(e8 >> 20);
    int i = (int)((e8 >> 8) & 4095);
    int h = (int)(e8 & 255);
    float di = dinv[k * NN_ + i];
    const size_t KIH = (size_t)KC * NN_ * HD;
    alignas(16) unsigned short p0[8], p1[8], p2[8], p3[8], o[8];
    *(vu4*)p0 = *(const vu4*)(pbuf + 0 * KIH + e8);
    *(vu4*)p1 = *(const vu4*)(pbuf + 1 * KIH + e8);
    *(vu4*)p2 = *(const vu4*)(pbuf + 2 * KIH + e8);
    *(vu4*)p3 = *(const vu4*)(pbuf + 3 * KIH + e8);
#pragma unroll
    for (int e = 0; e < 8; ++e) {
        float v = b2f(p0[e]) + b2f(p1[e]) + b2f(p2[e]) + b2f(p3[e]);
        o[e] = f2b(di * v + gnnb[k * HD + h + e]);
    }
    *(vu4*)(xt + e8) = *(vu4*)o;
}

// ---------------------------------------------------------------------------
// lstm_mm: NT GEMM with ALL 4 GATES PER LANE. Block = 128 rows x (32 ch x 4
// gates); waves 4x1 (wave = 32 rows); acc[2rt][2cc][4g] = 64 VGPR. B LDS is
// gate-grouped sB[g][ch][k]. Grid (8 chb, 96 bn); kk = bn>>5.
//   mode 0 (gateX): v += bih+bhh; store gX2[row][ch][4] (coalesced vus4).
//   mode 1 (step):  g = v + gX2; cell update with cbuf (f32); write c, h.
// ---------------------------------------------------------------------------
__global__ __launch_bounds__(256) void lstm_mm(const unsigned short* __restrict__ A,
        const unsigned short* __restrict__ W, const float* __restrict__ b1,
        const float* __restrict__ b2, unsigned short* __restrict__ gX2,
        float* __restrict__ cbuf, unsigned short* __restrict__ hbuf, int mode) {
    __shared__ __align__(16) unsigned short sA[128 * SA];     // 10.2 KB
    __shared__ __align__(16) unsigned short sB[4][32 * SA];   // 10.2 KB
    const int chb = blockIdx.x, bn = blockIdx.y;
    const int t = threadIdx.x, lane = t & 63, wave = t >> 6;
    const int m = lane & 15, q = lane >> 4, ko = q * 8;
    const int kk = bn >> 5;
    f32x4 acc[2][2][4] = {};   // [rt][cc][gate]
    const unsigned short* A0 = A + (size_t)bn * 128 * 256;
    const unsigned short* W0 = W + (size_t)kk * GD * 256 + (size_t)chb * 32 * 256;
    const int r = t >> 1, cS = (t & 1) << 4;   // A: 128 rows x 32 K
    const int gB = r >> 5, chB = r & 31;       // B: 4 g x 32 ch x 32 K
    for (int k0 = 0; k0 < 256; k0 += 32) {
        *(vu4*)(sA + r * SA + cS)     = *(const vu4*)(A0 + (size_t)r * 256 + k0 + cS);
        *(vu4*)(sA + r * SA + cS + 8) = *(const vu4*)(A0 + (size_t)r * 256 + k0 + cS + 8);
        const unsigned short* wsrc = W0 + (size_t)(gB * 256 + chB) * 256 + k0 + cS;
        *(vu4*)(&sB[gB][chB * SA + cS])     = *(const vu4*)wsrc;
        *(vu4*)(&sB[gB][chB * SA + cS + 8]) = *(const vu4*)(wsrc + 8);
        __syncthreads();
        short8 af[2];
#pragma unroll
        for (int rt = 0; rt < 2; ++rt)
            af[rt] = *(const short8*)(sA + (wave * 32 + rt * 16 + m) * SA + ko);
#pragma unroll
        for (int g = 0; g < 4; ++g)
#pragma unroll
            for (int cc = 0; cc < 2; ++cc) {
                short8 bf = *(const short8*)(&sB[g][(cc * 16 + m) * SA + ko]);
#pragma unroll
                for (int rt = 0; rt < 2; ++rt)
                    acc[rt][cc][g] = __builtin_amdgcn_mfma_f32_16x16x32_bf16(af[rt], bf, acc[rt][cc][g], 0, 0, 0);
            }
        __syncthreads();
    }
#pragma unroll
    for (int rt = 0; rt < 2; ++rt)
#pragma unroll
        for (int cc = 0; cc < 2; ++cc)
#pragma unroll
            for (int r2 = 0; r2 < 4; ++r2) {
                int row = bn * 128 + wave * 32 + rt * 16 + q * 4 + r2;   // 0..12287
                int ch = chb * 32 + cc * 16 + m;                          // 0..255
                size_t goff = ((size_t)row * 256 + ch) * 4;
                if (mode == 0) {
                    vus4 o;
#pragma unroll
                    for (int g = 0; g < 4; ++g) {
                        float v = acc[rt][cc][g][r2]
                                + b1[kk * GD + g * 256 + ch] + b2[kk * GD + g * 256 + ch];
                        o[g] = f2b(v);
                    }
                    *(vus4*)(gX2 + goff) = o;
                } else {
                    vus4 gv = *(const vus4*)(gX2 + goff);
                    float iv = acc[rt][cc][0][r2] + b2f(gv[0]);
                    float fv = acc[rt][cc][1][r2] + b2f(gv[1]);
                    float gg = acc[rt][cc][2][r2] + b2f(gv[2]);
                    float ov = acc[rt][cc][3][r2] + b2f(gv[3]);
                    size_t coff = (size_t)row * 256 + ch;
                    float cn = sigm(fv) * cbuf[coff] + sigm(iv) * tanhf(gg);
                    cbuf[coff] = cn;
                    hbuf[coff] = f2b(sigm(ov) * tanhf(cn));
                }
            }
}

// ---------------------------------------------------------------------------
// lstm_cell0: t=0 (h0=0,c0=0): c = sig(i)*tanh(g); h = sig(o)*tanh(c).
// ---------------------------------------------------------------------------
__global__ __launch_bounds__(256) void lstm_cell0(const unsigned short* __restrict__ gX2,
        float* __restrict__ cbuf, unsigned short* __restrict__ hbuf) {
    size_t e8 = ((size_t)blockIdx.x * 256 + threadIdx.x) * 8;
    size_t gb = e8 * 4;
    alignas(16) unsigned short gx[32], h8[8];
    alignas(16) float cv[8];
#pragma unroll
    for (int v = 0; v < 4; ++v)
        *(vu4*)(gx + v * 8) = *(const vu4*)(gX2 + gb + v * 8);
#pragma unroll
    for (int e = 0; e < 8; ++e) {
        float iv = b2f(gx[e * 4 + 0]), gg = b2f(gx[e * 4 + 2]), ov = b2f(gx[e * 4 + 3]);
        float cn = sigm(iv) * tanhf(gg);
        cv[e] = cn;
        h8[e] = f2b(sigm(ov) * tanhf(cn));
    }
    *(vf4*)(cbuf + e8)     = *(vf4*)cv;
    *(vf4*)(cbuf + e8 + 4) = *(vf4*)(cv + 4);
    *(vu4*)(hbuf + e8) = *(vu4*)h8;
}

// ---------------------------------------------------------------------------
// NT GEMM (fc): out[k][n][col] = tanh(A . W^T + b1). 64x64 tiles.
// ---------------------------------------------------------------------------
__global__ __launch_bounds__(256) void gemm_nt_ep(const unsigned short* __restrict__ A,
        const unsigned short* __restrict__ W, const float* __restrict__ b1,
        unsigned short* __restrict__ outp, int COLS, int do_tanh) {
    __shared__ __align__(16) unsigned short sA[64 * SA], sB[64 * SA];
    const int bg = blockIdx.x, bn = blockIdx.y, k = blockIdx.z;
    const int t = threadIdx.x, lane = t & 63, wave = t >> 6;
    const int m = lane & 15, q = lane >> 4, ko = q * 8;
    f32x4 acc[4] = {};
    const unsigned short* A0 = A + ((size_t)k * NN_ + bn * 64) * HD;
    const unsigned short* W0 = W + ((size_t)k * COLS + bg * 64) * HD;
    const int r = t >> 2, c8 = (t & 3) << 3;
    for (int k0 = 0; k0 < HD; k0 += 32) {
        *(vu4*)(sA + r * SA + c8) = *(const vu4*)(A0 + (size_t)r * HD + k0 + c8);
        *(vu4*)(sB + r * SA + c8) = *(const vu4*)(W0 + (size_t)r * HD + k0 + c8);
        __syncthreads();
        short8 af = *(const short8*)(sA + (wave * 16 + m) * SA + ko);
#pragma unroll
        for (int ct = 0; ct < 4; ++ct) {
            short8 bf = *(const short8*)(sB + (ct * 16 + m) * SA + ko);
            acc[ct] = __builtin_amdgcn_mfma_f32_16x16x32_bf16(af, bf, acc[ct], 0, 0, 0);
        }
        __syncthreads();
    }
#pragma unroll
    for (int ct = 0; ct < 4; ++ct)
#pragma unroll
        for (int r2 = 0; r2 < 4; ++r2) {
            int col = bg * 64 + ct * 16 + m;
            int row = bn * 64 + wave * 16 + q * 4 + r2;
            float v = acc[ct][r2];
            if (b1) v += b1[(size_t)k * COLS + col];
            if (do_tanh) v = tanhf(v);
            outp[((size_t)k * NN_ + row) * COLS + col] = f2b(v);
        }
}

// ---------------------------------------------------------------------------
// final_ep: pred = sig_slice(x + mean_k delta); res[n][f][k] = sig_slice(x + delta_k)
// ---------------------------------------------------------------------------
__global__ __launch_bounds__(256) void final_ep(const float* __restrict__ x,
        const unsigned short* __restrict__ delta, float* __restrict__ pred,
        float* __restrict__ res) {
    int idx = blockIdx.x * 256 + threadIdx.x;
    size_t base = (size_t)idx * 8;
    int f0 = (int)(base & 255);
    alignas(16) unsigned short d0[8], d1[8], d2[8];
    alignas(16) float pr[8], rs[24];
    vf4 xa = *(const vf4*)(x + base), xb = *(const vf4*)(x + base + 4);
    float xs[8] = { xa[0], xa[1], xa[2], xa[3], xb[0], xb[1], xb[2], xb[3] };
    *(vu4*)d0 = *(const vu4*)(delta + base);
    *(vu4*)d1 = *(const vu4*)(delta + (size_t)NN_ * FD + base);
    *(vu4*)d2 = *(const vu4*)(delta + 2 * (size_t)NN_ * FD + base);
#pragma unroll
    for (int e = 0; e < 8; ++e) {
        int f = f0 + e;
        bool sg = (f >= 10) && (f < 253);
        float xf = xs[e];
        float da = b2f(d0[e]), db = b2f(d1[e]), dc = b2f(d2[e]);
        float dm = (da + db + dc) * (1.f / 3.f);
        float p = xf + dm; if (sg) p = sigm(p);
        pr[e] = p;
        float z0 = xf + da; if (sg) z0 = sigm(z0);
        float z1 = xf + db; if (sg) z1 = sigm(z1);
        float z2 = xf + dc; if (sg) z2 = sigm(z2);
        rs[e * 3 + 0] = z0; rs[e * 3 + 1] = z1; rs[e * 3 + 2] = z2;
    }
    *(vf4*)(pred + base)     = *(vf4*)pr;
    *(vf4*)(pred + base + 4) = *(vf4*)(pr + 4);
    size_t rb = base * 3;
#pragma unroll
    for (int v = 0; v < 6; ++v)
        *(vf4*)(res + rb + v * 4) = *(vf4*)(rs + v * 4);
}

extern "C" void kernel_launch(void* const* d_in, const int* in_sizes, int n_in,
                              void* d_out, int out_size, void* d_ws, size_t ws_size,
                              hipStream_t stream) {
    const float* x    = (const float*)d_in[0];
    const float* gnnw = (const float*)d_in[1];
    const float* gnnb = (const float*)d_in[2];
    const float* wih  = (const float*)d_in[3];
    const float* whh  = (const float*)d_in[4];
    const float* bih  = (const float*)d_in[5];
    const float* bhh  = (const float*)d_in[6];
    const float* fcw  = (const float*)d_in[7];
    const float* fcb  = (const float*)d_in[8];
    const int*   adj  = (const int*)d_in[9];

    float* out = (float*)d_out;
    float* out_pred = out;
    float* out_res  = out + (size_t)NN_ * FD;
    float* out_adj  = out + (size_t)NN_ * FD * 4;

    // ws layout (~155 MB; ws is ~650+ MB per poison-fill evidence):
    char* ws = (char*)d_ws;
    float*          dinv  = (float*)ws;                          // 49,152
    unsigned short* R1    = (unsigned short*)(ws + 49152);       // 6,291,456 (yT -> h)
    unsigned short* R2    = (unsigned short*)(ws + 6340608);     // 6,291,456 (xt -> delta)
    unsigned short* wb    = (unsigned short*)(ws + 12632064);    // 3,538,944
    unsigned short* pbuf  = (unsigned short*)(ws + 16171008);    // 25,165,824
    unsigned short* gX2   = pbuf;                                // later lifetime
    unsigned short* abk   = (unsigned short*)(ws + 41336832);    // 100,663,296
    float*          cbuf  = (float*)(ws + 142000128);            // 12,582,912 -> 154,583,040
    const unsigned short* wihb = wb;
    const unsigned short* whhb = wb + 786432;
    const unsigned short* fcwb = wb + 1572864;
    (void)ws_size; (void)in_sizes; (void)n_in; (void)out_size;

    wcvt<<<dim3(864), 256, 0, stream>>>(wih, whh, fcw, wb);
    adj_pass<<<dim3(4096), 256, 0, stream>>>(adj, out_adj, abk, dinv);
    gemm_xw<<<dim3(64, 4, 3), 256, 0, stream>>>(x, gnnw, dinv, R1 /*yT*/);
    gemm_agg<<<dim3(2, 32, 12), 256, 0, stream>>>(abk, R1 /*yT*/, pbuf);
    agg_reduce<<<dim3(1536), 256, 0, stream>>>(pbuf, dinv, gnnb, R2 /*xt*/);
    // gateX: A=xt, W=wih, +biases -> gX2 (gate-interleaved)
    lstm_mm<<<dim3(8, 96), 256, 0, stream>>>(R2 /*xt*/, wihb, bih, bhh, gX2, nullptr, nullptr, 0);
    lstm_cell0<<<dim3(1536), 256, 0, stream>>>(gX2, cbuf, R1 /*h*/);
    for (int tstep = 1; tstep < 5; ++tstep)
        lstm_mm<<<dim3(8, 96), 256, 0, stream>>>(R1 /*h*/, whhb, nullptr, nullptr, gX2, cbuf, R1 /*h*/, 1);
    gemm_nt_ep<<<dim3(4, 64, 3), 256, 0, stream>>>(R1 /*h_last*/, fcwb, fcb, R2 /*delta*/, FD, 1);
    final_ep<<<dim3(512), 256, 0, stream>>>(x, R2 /*delta*/, out_pred, out_res);
}